// Round 17
// baseline (385.430 us; speedup 1.0000x reference)
//
#include <hip/hip_runtime.h>
#include <math.h>

#define B_     512
#define M_     196
#define N_     77
#define FEAT_  512
#define NCLS_  632
#define TDIM_  768
#define LDIM_  576
#define LS_EPS_ 0.1f
#define MARGIN_ 0.3f
#define BN_EPS_ 1e-5f
#define SINK_ITERS 8

typedef float fx4 __attribute__((ext_vector_type(4)));
typedef float fx8 __attribute__((ext_vector_type(8)));
typedef short sx8 __attribute__((ext_vector_type(8)));
typedef __bf16 bfx8 __attribute__((ext_vector_type(8)));

__device__ inline ushort f2bf(float f) {
  union { float f; uint u; } v; v.f = f;
  uint u = v.u;
  return (ushort)((u + 0x7FFFu + ((u >> 16) & 1u)) >> 16);
}
__device__ inline float bf2f(ushort b) {
  union { uint u; float f; } v; v.u = ((uint)b) << 16;
  return v.f;
}
__device__ inline sx8 cvt8(fx8 f) {
  bfx8 h = __builtin_convertvector(f, bfx8);
  return __builtin_bit_cast(sx8, h);
}
__device__ inline fx8 b2f8(sx8 s) {
  bfx8 h = __builtin_bit_cast(bfx8, s);
  return __builtin_convertvector(h, fx8);
}
__device__ inline fx4 mfma16(sx8 a, sx8 b, fx4 c) {
  return __builtin_amdgcn_mfma_f32_16x16x32_bf16(
      __builtin_bit_cast(bfx8, a), __builtin_bit_cast(bfx8, b), c, 0, 0, 0);
}
__device__ inline void gload_lds16(const void* g, void* l) {
  auto gp = (const __attribute__((address_space(1))) uint*)(uintptr_t)g;
  auto lp = (__attribute__((address_space(3))) uint*)(uintptr_t)l;
  __builtin_amdgcn_global_load_lds(gp, lp, 16, 0, 0);
}

// ===================== device bodies ========================================

// small bf16 MFMA GEMM body: 64x64 tile, BK=32 (teacher path)
__device__ inline void small_mfma_body(char* smem, int bx, int by,
                                       const float* __restrict__ A,
                                       const float* __restrict__ Wm,
                                       const float* __restrict__ bias,
                                       float* __restrict__ C, int N, int K) {
  ushort* ldsA = (ushort*)smem;
  ushort* ldsW = (ushort*)(smem + 4096);
  const int tid = threadIdx.x;
  const int lane = tid & 63;
  const int wv = tid >> 6;
  const int wr = wv >> 1, wc = wv & 1;
  const int row0 = by * 64;
  const int col0 = bx * 64;
  const int mt = tid >> 6;
  const int l16 = lane & 15;
  const int k8 = lane >> 4;

  const float* pA = A + (size_t)(row0 + mt * 16 + l16) * K + k8 * 8;
  int wcl = col0 + mt * 16 + l16;
  if (wcl >= N) wcl = N - 1;
  const float* pW = Wm + (size_t)wcl * K + k8 * 8;

  fx4 acc[2][2];
  const fx4 zz = {0.f, 0.f, 0.f, 0.f};
  acc[0][0] = zz; acc[0][1] = zz; acc[1][0] = zz; acc[1][1] = zz;

  sx8 ua = cvt8(*(const fx8*)pA);
  sx8 uw = cvt8(*(const fx8*)pW);
  const int NT = K >> 5;
  for (int kt = 0; kt < NT; ++kt) {
    if (kt) __syncthreads();
    *(sx8*)&ldsA[tid * 8] = ua;
    *(sx8*)&ldsW[tid * 8] = uw;
    __syncthreads();
    if (kt + 1 < NT) {
      ua = cvt8(*(const fx8*)(pA + (kt + 1) * 32));
      uw = cvt8(*(const fx8*)(pW + (kt + 1) * 32));
    }
    sx8 af[2], bf[2];
#pragma unroll
    for (int mi = 0; mi < 2; ++mi) af[mi] = *(sx8*)&ldsA[((wr * 2 + mi) * 64 + lane) * 8];
#pragma unroll
    for (int ni = 0; ni < 2; ++ni) bf[ni] = *(sx8*)&ldsW[((wc * 2 + ni) * 64 + lane) * 8];
#pragma unroll
    for (int mi = 0; mi < 2; ++mi)
#pragma unroll
      for (int ni = 0; ni < 2; ++ni) acc[mi][ni] = mfma16(af[mi], bf[ni], acc[mi][ni]);
  }
#pragma unroll
  for (int mi = 0; mi < 2; ++mi) {
    int rbase = row0 + (wr * 2 + mi) * 16 + ((lane >> 4) << 2);
#pragma unroll
    for (int ni = 0; ni < 2; ++ni) {
      int col = col0 + (wc * 2 + ni) * 16 + l16;
      if (col < N) {
        float bv = bias ? bias[col] : 0.f;
#pragma unroll
        for (int r = 0; r < 4; ++r)
          C[(size_t)(rbase + r) * N + col] = acc[mi][ni][r] + bv;
      }
    }
  }
}

// f32 exact GEMM body (student path): 32x32 tile
__device__ inline void gemm_nt32_body(char* smem, int bx, int by,
                                      const float* __restrict__ A,
                                      const float* __restrict__ W,
                                      const float* __restrict__ bias,
                                      float* __restrict__ C, int Mr, int N, int K) {
  float (*As)[33] = (float (*)[33])smem;
  float (*Ws)[33] = (float (*)[33])(smem + 4224);
  const int tid = threadIdx.x;
  const int tx = tid & 15, ty = tid >> 4;
  const int row0 = by * 32;
  const int col0 = bx * 32;
  float acc[2][2] = {{0.f, 0.f}, {0.f, 0.f}};

  for (int k0 = 0; k0 < K; k0 += 32) {
#pragma unroll
    for (int e = tid; e < 32 * 32; e += 256) {
      int r = e / 32, c = e % 32;
      int gr = row0 + r, gc = k0 + c;
      As[r][c] = (gr < Mr && gc < K) ? A[(size_t)gr * K + gc] : 0.f;
    }
#pragma unroll
    for (int e = tid; e < 32 * 32; e += 256) {
      int r = e / 32, c = e % 32;
      int gr = col0 + r, gc = k0 + c;
      Ws[r][c] = (gr < N && gc < K) ? W[(size_t)gr * K + gc] : 0.f;
    }
    __syncthreads();
#pragma unroll
    for (int kk = 0; kk < 32; ++kk) {
      float a[2], wv[2];
#pragma unroll
      for (int i = 0; i < 2; ++i) a[i] = As[ty * 2 + i][kk];
#pragma unroll
      for (int j = 0; j < 2; ++j) wv[j] = Ws[tx * 2 + j][kk];
#pragma unroll
      for (int i = 0; i < 2; ++i)
#pragma unroll
        for (int j = 0; j < 2; ++j) acc[i][j] += a[i] * wv[j];
    }
    __syncthreads();
  }
#pragma unroll
  for (int i = 0; i < 2; ++i) {
    int gr = row0 + ty * 2 + i;
    if (gr >= Mr) continue;
#pragma unroll
    for (int j = 0; j < 2; ++j) {
      int gc = col0 + tx * 2 + j;
      if (gc >= N) continue;
      float v = acc[i][j];
      if (bias) v += bias[gc];
      C[(size_t)gr * N + gc] = v;
    }
  }
}

// batchnorm body (one block per feature)
__device__ inline void bn_body(char* pool, int j,
                               const float* __restrict__ X, float* __restrict__ Y,
                               const float* __restrict__ g, const float* __restrict__ b) {
  const int tid = threadIdx.x;
  float* sf = (float*)pool;
  float vals[2];
  float s = 0.f, s2 = 0.f;
  int idx = 0;
  for (int i = tid; i < B_; i += 256, ++idx) {
    float v = X[(size_t)i * FEAT_ + j];
    vals[idx] = v;
    s += v; s2 += v * v;
  }
  sf[tid] = s; __syncthreads();
  for (int k = 128; k > 0; k >>= 1) { if (tid < k) sf[tid] += sf[tid + k]; __syncthreads(); }
  float mu = sf[0] * (1.f / B_); __syncthreads();
  sf[tid] = s2; __syncthreads();
  for (int k = 128; k > 0; k >>= 1) { if (tid < k) sf[tid] += sf[tid + k]; __syncthreads(); }
  float var = sf[0] * (1.f / B_) - mu * mu;
  float scale = rsqrtf(var + BN_EPS_) * g[j];
  float shift = b[j];
  idx = 0;
  for (int i = tid; i < B_; i += 256, ++idx)
    Y[(size_t)i * FEAT_ + j] = (vals[idx] - mu) * scale + shift;
}

// fused CE(t) + CE(s)+preds + KL body
__device__ inline void ce_kl_body(char* pool, int row,
                                  const float* __restrict__ TL,
                                  const float* __restrict__ SL,
                                  const int* __restrict__ label,
                                  float* __restrict__ acc,
                                  float* __restrict__ preds) {
  const int tid = threadIdx.x;
  const float* tp = TL + (size_t)row * NCLS_;
  const float* sp = SL + (size_t)row * NCLS_;
  float (*red)[256] = (float (*)[256])pool;
  int* ridx = (int*)(pool + 4096);
  float* sxl = (float*)(pool + 5120);

  float tv[3], sv[3];
#pragma unroll
  for (int k = 0; k < 3; ++k) {
    int j = tid + k * 256;
    tv[k] = (j < NCLS_) ? tp[j] : -INFINITY;
    sv[k] = (j < NCLS_) ? sp[j] : -INFINITY;
  }
  float mT = -INFINITY, mS = -INFINITY, sT = 0.f, sS = 0.f;
  int ai = NCLS_;
#pragma unroll
  for (int k = 0; k < 3; ++k) {
    int j = tid + k * 256;
    if (j < NCLS_) {
      mT = fmaxf(mT, tv[k]);
      sT += tv[k]; sS += sv[k];
      if (sv[k] > mS) { mS = sv[k]; ai = j; }
    }
  }
  red[0][tid] = mT; red[1][tid] = mS; red[2][tid] = sT; red[3][tid] = sS; ridx[tid] = ai;
  __syncthreads();
  for (int k = 128; k > 0; k >>= 1) {
    if (tid < k) {
      red[0][tid] = fmaxf(red[0][tid], red[0][tid + k]);
      float om = red[1][tid + k]; int oi = ridx[tid + k];
      if (om > red[1][tid] || (om == red[1][tid] && oi < ridx[tid])) { red[1][tid] = om; ridx[tid] = oi; }
      red[2][tid] += red[2][tid + k];
      red[3][tid] += red[3][tid + k];
    }
    __syncthreads();
  }
  const float MT = red[0][0], MS = red[1][0], sumT = red[2][0], sumS = red[3][0];
  const int amax = ridx[0];
  __syncthreads();
  float etr = 0.f, esr = 0.f, eth = 0.f, esh = 0.f;
#pragma unroll
  for (int k = 0; k < 3; ++k) {
    int j = tid + k * 256;
    if (j < NCLS_) {
      etr += expf(tv[k] - MT);
      esr += expf(sv[k] - MS);
      eth += expf(0.5f * (tv[k] - MT));
      esh += expf(0.5f * (sv[k] - MS));
    }
  }
  red[0][tid] = etr; red[1][tid] = esr; red[2][tid] = eth; red[3][tid] = esh;
  __syncthreads();
  for (int k = 128; k > 0; k >>= 1) {
    if (tid < k) {
      red[0][tid] += red[0][tid + k];
      red[1][tid] += red[1][tid + k];
      red[2][tid] += red[2][tid + k];
      red[3][tid] += red[3][tid + k];
    }
    __syncthreads();
  }
  const float lseT = MT + logf(red[0][0]);
  const float lseS = MS + logf(red[1][0]);
  const float ltH = 0.5f * MT + logf(red[2][0]);
  const float lsH = 0.5f * MS + logf(red[3][0]);
  __syncthreads();
  const int lab = label[row];
  float klp = 0.f;
#pragma unroll
  for (int k = 0; k < 3; ++k) {
    int j = tid + k * 256;
    if (j < NCLS_) {
      float tlp = 0.5f * tv[k] - ltH;
      float slp = 0.5f * sv[k] - lsH;
      klp += expf(tlp) * (tlp - slp);
      if (j == lab) { sxl[0] = tv[k]; sxl[1] = sv[k]; }
    }
  }
  red[0][tid] = klp;
  __syncthreads();
  for (int k = 128; k > 0; k >>= 1) {
    if (tid < k) red[0][tid] += red[0][tid + k];
    __syncthreads();
  }
  if (tid == 0) {
    float ce_t = -((1.f - LS_EPS_) * (sxl[0] - lseT) + (LS_EPS_ / NCLS_) * (sumT - NCLS_ * lseT));
    float ce_s = -((1.f - LS_EPS_) * (sxl[1] - lseS) + (LS_EPS_ / NCLS_) * (sumS - NCLS_ * lseS));
    atomicAdd(acc + 0, ce_t * (1.f / B_));
    atomicAdd(acc + 2, ce_s * (1.f / B_));
    atomicAdd(acc + 4, red[0][0] * (1.f / B_));
    preds[row] = (float)amax;
  }
}

// triplet hard-mining body
__device__ inline void triplet_body(char* pool, int which, int i,
                                    const float* __restrict__ Gt,
                                    const float* __restrict__ Gs,
                                    const int* __restrict__ label,
                                    float* __restrict__ acc) {
  const float* G = which ? Gs : Gt;
  float* a = acc + (which ? 3 : 1);
  const int tid = threadIdx.x;
  const int li = label[i];
  float* sap = (float*)pool;
  float* san = (float*)(pool + 1024);
  const float sqi = G[(size_t)i * B_ + i];
  float ap = -INFINITY, an = INFINITY;
  for (int j = tid; j < B_; j += 256) {
    float sqj = G[(size_t)j * B_ + j];
    float d2 = sqi + sqj - 2.f * G[(size_t)i * B_ + j];
    float d = sqrtf(fmaxf(d2, 1e-12f));
    if (label[j] == li) ap = fmaxf(ap, d); else an = fminf(an, d);
  }
  sap[tid] = ap; san[tid] = an; __syncthreads();
  for (int k = 128; k > 0; k >>= 1) {
    if (tid < k) {
      sap[tid] = fmaxf(sap[tid], sap[tid + k]);
      san[tid] = fminf(san[tid], san[tid + k]);
    }
    __syncthreads();
  }
  if (tid == 0) atomicAdd(a, fmaxf(sap[0] - san[0] + MARGIN_, 0.f) * (1.f / B_));
}

// per-batch Sinkhorn body (bf16 K + K^T in pool LDS)
#define SKLD 88
#define SKTLD 200
__device__ inline void sinkhorn_body(char* pool, int b,
                                     const ushort* __restrict__ sim,
                                     float* __restrict__ acc) {
  const int tid = threadIdx.x;
  ushort* Kb  = (ushort*)pool;               // 34496 B
  ushort* KbT = (ushort*)(pool + 34496);     // 30800 B
  float* r    = (float*)(pool + 65296);
  float* c    = (float*)(pool + 66080);
  float* sf   = (float*)(pool + 66432);
  float* cs1  = (float*)(pool + 67456);
  const ushort* simb = sim + (size_t)b * (M_ * N_);
  for (int e = tid; e < 196 * SKLD; e += 256) {
    int m = e / SKLD, n = e - m * SKLD;
    if (n < 77) {
      float sv = bf2f(simb[m * 77 + n]);
      ushort h = f2bf(__expf((sv - 1.f) * 10.f));
      Kb[e] = h;
      KbT[n * SKTLD + m] = h;
    } else Kb[e] = 0;
  }
  if (tid < SKLD) c[tid] = (tid < 77) ? 1.f : 0.f;
  __syncthreads();
  const float uu = 1.f / 196.f, vv = 1.f / 77.f;
  for (int it = 0; it < SINK_ITERS; ++it) {
    if (tid < 196) {
      const ushort* Km = &Kb[tid * SKLD];
      float s = 0.f;
#pragma unroll
      for (int j = 0; j < 11; ++j) {
        fx8 kf = b2f8(*(const sx8*)&Km[j * 8]);
#pragma unroll
        for (int q = 0; q < 8; ++q) s += kf[q] * c[j * 8 + q];
      }
      r[tid] = uu / s;
    }
    __syncthreads();
    if (tid < 154) {
      const int half = (tid >= 77) ? 1 : 0;
      const int n = tid - 77 * half;
      const ushort* Kn = &KbT[n * SKTLD + 96 * half];
      const int m0 = 96 * half;
      float s = 0.f;
#pragma unroll
      for (int j = 0; j < 12; ++j) {
        fx8 kf = b2f8(*(const sx8*)&Kn[j * 8]);
#pragma unroll
        for (int q = 0; q < 8; ++q) s += kf[q] * r[m0 + j * 8 + q];
      }
      if (half) {
        s += bf2f(Kn[96]) * r[192] + bf2f(Kn[97]) * r[193]
           + bf2f(Kn[98]) * r[194] + bf2f(Kn[99]) * r[195];
        cs1[n] = s;
      } else sf[n] = s;
    }
    __syncthreads();
    if (tid < 77) c[tid] = vv / (sf[tid] + cs1[tid]);
    __syncthreads();
  }
  float part = 0.f;
  for (int e = tid; e < M_ * N_; e += 256) {
    int m = e / 77, n = e - m * 77;
    part += r[m] * c[n] * bf2f(Kb[m * SKLD + n]) * bf2f(simb[e]);
  }
  sf[tid] = part; __syncthreads();
  for (int k = 128; k > 0; k >>= 1) { if (tid < k) sf[tid] += sf[tid + k]; __syncthreads(); }
  if (tid == 0) atomicAdd(acc + 5, sf[0] * (1.f / B_));
}

// ===== batched cosine sim: 3-way M-split, BK=64 phases, paired 64B staging ==
template<int H>
__device__ void sim_body(int b, const float* __restrict__ S, const ushort* __restrict__ T,
                         ushort* __restrict__ sim, ushort* lds, float* sinv_s, float* tinv_s) {
  constexpr int NTILE = (H == 2) ? 5 : 4;
  constexpr int SCH = NTILE * 128;
  constexpr int NPAIR = (SCH + 640) / 2;
  constexpr int M0 = H * 64;
  const int tid = threadIdx.x;
  const int lane = tid & 63;
  const int w = tid >> 6;

  bool val[3], isS[3], k0th[3];
  const float* pS[3];
  const ushort* pT[3];
  int rowi[3], c0[3];
#pragma unroll
  for (int j = 0; j < 3; ++j) {
    int pp = tid + j * 256;
    val[j] = (pp < NPAIR);
    int tile = pp >> 6;
    int idx = pp & 63;
    int row16 = idx & 15;
    int k8e = (idx >> 4) * 2;
    k0th[j] = (k8e == 0);
    c0[j] = tile * 128 + row16 + 16 * k8e;
    isS[j] = (tile < NTILE);
    if (isS[j]) {
      int r = M0 + tile * 16 + row16;
      int rr = r < 196 ? r : 195;
      pS[j] = S + ((size_t)b * M_ + rr) * LDIM_ + k8e * 8;
      rowi[j] = rr - M0;
      pT[j] = T;
    } else {
      int t = tile - NTILE;
      int r = t * 16 + row16;
      int rr = r < 77 ? r : 76;
      pT[j] = T + ((size_t)b * N_ + rr) * LDIM_ + k8e * 8;
      pS[j] = S;
      rowi[j] = rr;
    }
  }

  fx8 fa[3], fb[3]; sx8 ta[3], tb[3];
#pragma unroll
  for (int j = 0; j < 3; ++j) {
    if (!val[j]) continue;
    if (isS[j]) { fa[j] = *(const fx8*)pS[j]; fb[j] = *(const fx8*)(pS[j] + 8); }
    else        { ta[j] = *(const sx8*)pT[j]; tb[j] = *(const sx8*)(pT[j] + 8); }
  }

  float ss[3] = {0.f, 0.f, 0.f};
  fx4 acc[2][5];
  const fx4 zz = {0.f, 0.f, 0.f, 0.f};
#pragma unroll
  for (int i = 0; i < 2; ++i)
#pragma unroll
    for (int j = 0; j < 5; ++j) acc[i][j] = zz;

  for (int kt = 0; kt < 9; ++kt) {
    if (kt) __syncthreads();
#pragma unroll
    for (int j = 0; j < 3; ++j) {
      if (!val[j]) continue;
      if (isS[j]) {
        *(sx8*)&lds[c0[j] * 8] = cvt8(fa[j]);
        *(sx8*)&lds[(c0[j] + 16) * 8] = cvt8(fb[j]);
#pragma unroll
        for (int q = 0; q < 8; ++q) ss[j] += fa[j][q] * fa[j][q] + fb[j][q] * fb[j][q];
      } else {
        *(sx8*)&lds[c0[j] * 8] = ta[j];
        *(sx8*)&lds[(c0[j] + 16) * 8] = tb[j];
        fx8 tfa = b2f8(ta[j]), tfb = b2f8(tb[j]);
#pragma unroll
        for (int q = 0; q < 8; ++q) ss[j] += tfa[q] * tfa[q] + tfb[q] * tfb[q];
      }
    }
    if (kt < 8) {
      const int ko = (kt + 1) * 64;
#pragma unroll
      for (int j = 0; j < 3; ++j) {
        if (!val[j]) continue;
        if (isS[j]) { fa[j] = *(const fx8*)(pS[j] + ko); fb[j] = *(const fx8*)(pS[j] + ko + 8); }
        else        { ta[j] = *(const sx8*)(pT[j] + ko); tb[j] = *(const sx8*)(pT[j] + ko + 8); }
      }
    }
    __syncthreads();
#pragma unroll
    for (int q = 0; q < 2; ++q) {
      sx8 bfr[5];
#pragma unroll
      for (int ni = 0; ni < 5; ++ni)
        bfr[ni] = *(sx8*)&lds[(SCH + ni * 128 + 64 * q + lane) * 8];
#pragma unroll
      for (int mi = 0; mi < 2; ++mi) {
        int lt = w + mi * 4;
        if (lt < NTILE) {
          sx8 af = *(sx8*)&lds[(lt * 128 + 64 * q + lane) * 8];
#pragma unroll
          for (int ni = 0; ni < 5; ++ni) acc[mi][ni] = mfma16(af, bfr[ni], acc[mi][ni]);
        }
      }
    }
  }

#pragma unroll
  for (int j = 0; j < 3; ++j) {
    if (!val[j]) continue;
    float s = ss[j];
    s += __shfl_xor(s, 16);
    s += __shfl_xor(s, 32);
    if (k0th[j]) {
      float inv = 1.f / fmaxf(sqrtf(s), 1e-12f);
      if (isS[j]) sinv_s[rowi[j]] = inv;
      else        tinv_s[rowi[j]] = inv;
    }
  }
  __syncthreads();

#pragma unroll
  for (int mi = 0; mi < 2; ++mi) {
    int lt = w + mi * 4;
    if (lt >= NTILE) continue;
    int lrbase = lt * 16 + ((lane >> 4) << 2);
#pragma unroll
    for (int ni = 0; ni < 5; ++ni) {
      int col = ni * 16 + (lane & 15);
      if (col < 77) {
        float tv = tinv_s[col];
#pragma unroll
        for (int r = 0; r < 4; ++r) {
          int lrow = lrbase + r;
          int row = M0 + lrow;
          if (row < 196)
            sim[((size_t)b * M_ + row) * N_ + col] = f2bf(acc[mi][ni][r] * sinv_s[lrow] * tv);
        }
      }
    }
  }
}

// ttext 128x128 GEMM body, BK=32 double-buffered (loads overlap MFMA)
__device__ inline void gemm128_body(char* pool, int bx, int by,
                                    const ushort* __restrict__ A,
                                    const ushort* __restrict__ Bm,
                                    const float* __restrict__ bias,
                                    ushort* __restrict__ C) {
  ushort* ldsA = (ushort*)pool;              // 2 buffers x 4096 ushorts (8KB each)
  ushort* ldsB = (ushort*)(pool + 16384);    // 2 buffers x 4096 ushorts
  const int tid = threadIdx.x;
  const int lane = tid & 63;
  const int w = tid >> 6;
  const int wr = w >> 1, wc = w & 1;
  const int row0 = by * 128;
  const int col0 = bx * 128;
  const int l16 = lane & 15, k8 = (lane >> 4) * 8;

  const ushort* gA0 = A + (size_t)(row0 + (2 * w) * 16 + l16) * TDIM_ + k8;
  const ushort* gA1 = A + (size_t)(row0 + (2 * w + 1) * 16 + l16) * TDIM_ + k8;
  const ushort* gB0 = Bm + (size_t)(col0 + (2 * w) * 16 + l16) * TDIM_ + k8;
  const ushort* gB1 = Bm + (size_t)(col0 + (2 * w + 1) * 16 + l16) * TDIM_ + k8;
  // within a buffer, tile t occupies 512 ushorts at [t*512]
  ushort* lA0 = &ldsA[(2 * w) * 512];
  ushort* lA1 = &ldsA[(2 * w + 1) * 512];
  ushort* lB0 = &ldsB[(2 * w) * 512];
  ushort* lB1 = &ldsB[(2 * w + 1) * 512];

  fx4 acc[4][4];
  const fx4 zz = {0.f, 0.f, 0.f, 0.f};
#pragma unroll
  for (int i = 0; i < 4; ++i)
#pragma unroll
    for (int j = 0; j < 4; ++j) acc[i][j] = zz;

  // prologue: stage kt=0 into buffer 0
  gload_lds16(gA0, lA0);
  gload_lds16(gA1, lA1);
  gload_lds16(gB0, lB0);
  gload_lds16(gB1, lB1);
  asm volatile("s_waitcnt vmcnt(0)" ::: "memory");
  __syncthreads();

  for (int kt = 0; kt < 24; ++kt) {
    const int cur = (kt & 1) * 4096;
    const int nxt = ((kt + 1) & 1) * 4096;
    if (kt + 1 < 24) {
      const int ko = (kt + 1) * 32;
      gload_lds16(gA0 + ko, lA0 + nxt);
      gload_lds16(gA1 + ko, lA1 + nxt);
      gload_lds16(gB0 + ko, lB0 + nxt);
      gload_lds16(gB1 + ko, lB1 + nxt);
    }
    sx8 af[4], bf[4];
#pragma unroll
    for (int mi = 0; mi < 4; ++mi) af[mi] = *(sx8*)&ldsA[cur + ((wr * 4 + mi) * 64 + lane) * 8];
#pragma unroll
    for (int ni = 0; ni < 4; ++ni) bf[ni] = *(sx8*)&ldsB[cur + ((wc * 4 + ni) * 64 + lane) * 8];
#pragma unroll
    for (int mi = 0; mi < 4; ++mi)
#pragma unroll
      for (int ni = 0; ni < 4; ++ni) acc[mi][ni] = mfma16(af[mi], bf[ni], acc[mi][ni]);
    asm volatile("s_waitcnt vmcnt(0)" ::: "memory");
    __syncthreads();
  }

#pragma unroll
  for (int mi = 0; mi < 4; ++mi) {
    int rbase = row0 + wr * 64 + mi * 16 + ((lane >> 4) << 2);
#pragma unroll
    for (int ni = 0; ni < 4; ++ni) {
      int col = col0 + wc * 64 + ni * 16 + l16;
      if (col < 576) {
        float bv = bias[col];
#pragma unroll
        for (int r = 0; r < 4; ++r)
          C[(size_t)(rbase + r) * 576 + col] = f2bf(acc[mi][ni][r] + bv);
      }
    }
  }
}

// ===================== merged launch kernels ================================

// LA: stage1 (tlin MFMA + sglob f32) || prep (W cvt + acc zero) || cvt text
__global__ __launch_bounds__(256) void kernel_A(const float* __restrict__ t_img_raw,
                                                const float* __restrict__ W_tv,
                                                const float* __restrict__ b_tv,
                                                float* __restrict__ tlin,
                                                const float* __restrict__ s_glob_raw,
                                                const float* __restrict__ W_sv,
                                                const float* __restrict__ b_sv,
                                                float* __restrict__ sglob,
                                                const float* __restrict__ W_tt,
                                                ushort* __restrict__ Wbuf,
                                                float* __restrict__ acc,
                                                const float* __restrict__ text_feat,
                                                ushort* __restrict__ Abuf) {
  __shared__ __align__(16) char pool[8448];
  const int bid = blockIdx.x;
  const int tid = threadIdx.x;
  if (bid < 64) {
    small_mfma_body(pool, bid & 7, bid >> 3, t_img_raw, W_tv, b_tv, tlin, FEAT_, TDIM_);
  } else if (bid < 320) {
    int i = bid - 64;
    gemm_nt32_body(pool, i & 15, i >> 4, s_glob_raw, W_sv, b_sv, sglob, 512, FEAT_, LDIM_);
  } else if (bid < 561) {
    int pbid = bid - 320;
    if (pbid == 240) {
      if (tid < 8) acc[tid] = 0.f;
      return;
    }
    int i = pbid * 256 + tid;
    int row = i / 96;
    if (row < 576) {
      fx8 f = *(const fx8*)(W_tt + (size_t)i * 8);
      *(sx8*)(Wbuf + (size_t)i * 8) = cvt8(f);
    } else {
      sx8 z = {0, 0, 0, 0, 0, 0, 0, 0};
      *(sx8*)(Wbuf + (size_t)i * 8) = z;
    }
  } else {
    size_t i = (size_t)(bid - 561) * 256 + tid;
    fx8 f = *(const fx8*)(text_feat + i * 8);
    *(sx8*)(Abuf + i * 8) = cvt8(f);
  }
}

// LB: gemm_bf16_128 dbuf (XCD-swizzled, global_load_lds) || bn
__global__ __launch_bounds__(256) void kernel_B(const ushort* __restrict__ Abuf,
                                                const ushort* __restrict__ Wbuf,
                                                const float* __restrict__ b_tt,
                                                ushort* __restrict__ ttext,
                                                const float* __restrict__ tlin,
                                                float* __restrict__ timg,
                                                const float* __restrict__ bn_g,
                                                const float* __restrict__ bn_b) {
  __shared__ __align__(16) char pool[32768];
  const int bid = blockIdx.x;
  if (bid < 1540) {
    const int xcd = bid & 7, wi = bid >> 3;
    const int swz = (xcd < 4 ? xcd * 193 : 772 + (xcd - 4) * 192) + wi;
    const int by = swz / 5, bx = swz - by * 5;
    gemm128_body(pool, bx, by, Abuf, Wbuf, b_tt, ttext);
  } else {
    bn_body(pool, bid - 1540, tlin, timg, bn_g, bn_b);
  }
}

// LC: sim (XCD-swizzled, BK=64 paired staging) || stage2
__global__ __launch_bounds__(256) void kernel_C(const float* __restrict__ s_local,
                                                const ushort* __restrict__ ttext,
                                                ushort* __restrict__ sim,
                                                const float* __restrict__ timg,
                                                const float* __restrict__ W_ct,
                                                const float* __restrict__ b_ct,
                                                float* __restrict__ tlog,
                                                const float* __restrict__ sglob,
                                                const float* __restrict__ W_cs,
                                                const float* __restrict__ b_cs,
                                                float* __restrict__ slog,
                                                float* __restrict__ gram_t,
                                                float* __restrict__ gram_s) {
  __shared__ __align__(16) char pool[21120];
  const int bid = blockIdx.x;
  if (bid < 1536) {
    ushort* lds = (ushort*)pool;
    float* sinv_s = (float*)(pool + 20480);
    float* tinv_s = (float*)(pool + 20800);
    const int swz = (bid & 7) * 192 + (bid >> 3);
    const int b = swz / 3;
    const int q = swz - b * 3;
    if (q == 0)      sim_body<0>(b, s_local, ttext, sim, lds, sinv_s, tinv_s);
    else if (q == 1) sim_body<1>(b, s_local, ttext, sim, lds, sinv_s, tinv_s);
    else             sim_body<2>(b, s_local, ttext, sim, lds, sinv_s, tinv_s);
  } else {
    int i = bid - 1536;
    if (i < 80) {
      small_mfma_body(pool, i % 10, i / 10, timg, W_ct, b_ct, tlog, NCLS_, FEAT_);
    } else if (i < 400) {
      int j = i - 80;
      gemm_nt32_body(pool, j % 20, j / 20, sglob, W_cs, b_cs, slog, 512, NCLS_, FEAT_);
    } else if (i < 464) {
      int j = i - 400;
      small_mfma_body(pool, j & 7, j >> 3, timg, timg, nullptr, gram_t, 512, FEAT_);
    } else {
      int j = i - 464;
      small_mfma_body(pool, j & 7, j >> 3, sglob, sglob, nullptr, gram_s, 512, LDIM_);
    }
  }
}

// LD: sinkhorn || ce_kl (+preds) || triplet x2, with device-wide completion
__global__ __launch_bounds__(256) void kernel_D(const ushort* __restrict__ sim,
                                                const float* __restrict__ tlog,
                                                const float* __restrict__ slog,
                                                const float* __restrict__ gram_t,
                                                const float* __restrict__ gram_s,
                                                const int* __restrict__ label,
                                                float* __restrict__ acc,
                                                float* __restrict__ out) {
  __shared__ __align__(16) char pool[67840];
  const int bid = blockIdx.x;
  if (bid < 512) {
    sinkhorn_body(pool, bid, sim, acc);
  } else if (bid < 1024) {
    ce_kl_body(pool, bid - 512, tlog, slog, label, acc, out + 1);
  } else {
    int i = bid - 1024;
    triplet_body(pool, i >> 9, i & 511, gram_t, gram_s, label, acc);
  }
  if (threadIdx.x == 0) {
    __threadfence();
    uint prev = atomicAdd((uint*)(acc + 6), 1u);
    if (prev == 2047u) {
      float a0 = atomicAdd(acc + 0, 0.f);
      float a1 = atomicAdd(acc + 1, 0.f);
      float a2 = atomicAdd(acc + 2, 0.f);
      float a3 = atomicAdd(acc + 3, 0.f);
      float a4 = atomicAdd(acc + 4, 0.f);
      float a5 = atomicAdd(acc + 5, 0.f);
      out[0] = a0 + a1 + a2 + a3 + a4 + (1.f - a5);
    }
  }
}

// ---------------------------------------------------------------------------
extern "C" void kernel_launch(void* const* d_in, const int* in_sizes, int n_in,
                              void* d_out, int out_size, void* d_ws, size_t ws_size,
                              hipStream_t stream) {
  const float* text_feat  = (const float*)d_in[0];
  const float* t_img_raw  = (const float*)d_in[1];
  const float* s_glob_raw = (const float*)d_in[2];
  const float* s_local    = (const float*)d_in[3];
  const int*   label      = (const int*)d_in[4];
  const float* W_tv = (const float*)d_in[5];
  const float* b_tv = (const float*)d_in[6];
  const float* W_tt = (const float*)d_in[7];
  const float* b_tt = (const float*)d_in[8];
  const float* W_sv = (const float*)d_in[9];
  const float* b_sv = (const float*)d_in[10];
  const float* bn_g = (const float*)d_in[11];
  const float* bn_b = (const float*)d_in[12];
  const float* W_ct = (const float*)d_in[13];
  const float* b_ct = (const float*)d_in[14];
  const float* W_cs = (const float*)d_in[15];
  const float* b_cs = (const float*)d_in[16];
  float* out = (float*)d_out;
  float* ws = (float*)d_ws;

  float* tlin   = ws;
  float* timg   = tlin + 262144;
  float* sglob  = timg + 262144;
  float* tlog   = sglob + 262144;
  float* slog   = tlog + 323584;
  float* gram_t = slog + 323584;
  float* gram_s = gram_t + 262144;
  float* acc    = gram_s + 262144;
  ushort* Wbuf  = (ushort*)(acc + 8);
  ushort* ttext = Wbuf + 491520;
  ushort* Abuf  = ttext + 22708224;
  ushort* sim   = Abuf;   // alias; Abuf dead before sim written

  dim3 blk(256);

  // LA: stage1 || prep || cvt
  kernel_A<<<15345, blk, 0, stream>>>(t_img_raw, W_tv, b_tv, tlin,
                                      s_glob_raw, W_sv, b_sv, sglob,
                                      W_tt, Wbuf, acc, text_feat, Abuf);
  // LB: ttext GEMM (dbuf) || bn
  kernel_B<<<2052, blk, 0, stream>>>(Abuf, Wbuf, b_tt, ttext, tlin, timg, bn_g, bn_b);
  // LC: sim (BK=64) || stage2
  kernel_C<<<2064, blk, 0, stream>>>(s_local, ttext, sim,
                                     timg, W_ct, b_ct, tlog,
                                     sglob, W_cs, b_cs, slog, gram_t, gram_s);
  // LD: sinkhorn || ce_kl || triplet, fused finalize
  kernel_D<<<2048, blk, 0, stream>>>(sim, tlog, slog, gram_t, gram_s, label, acc, out);
}

// Round 18
// 376.971 us; speedup vs baseline: 1.0224x; 1.0224x over previous
//
#include <hip/hip_runtime.h>
#include <math.h>

#define B_     512
#define M_     196
#define N_     77
#define FEAT_  512
#define NCLS_  632
#define TDIM_  768
#define LDIM_  576
#define LS_EPS_ 0.1f
#define MARGIN_ 0.3f
#define BN_EPS_ 1e-5f
#define SINK_ITERS 8

typedef float fx4 __attribute__((ext_vector_type(4)));
typedef float fx8 __attribute__((ext_vector_type(8)));
typedef short sx8 __attribute__((ext_vector_type(8)));
typedef __bf16 bfx8 __attribute__((ext_vector_type(8)));

__device__ inline ushort f2bf(float f) {
  union { float f; uint u; } v; v.f = f;
  uint u = v.u;
  return (ushort)((u + 0x7FFFu + ((u >> 16) & 1u)) >> 16);
}
__device__ inline float bf2f(ushort b) {
  union { uint u; float f; } v; v.u = ((uint)b) << 16;
  return v.f;
}
__device__ inline sx8 cvt8(fx8 f) {
  bfx8 h = __builtin_convertvector(f, bfx8);
  return __builtin_bit_cast(sx8, h);
}
__device__ inline fx8 b2f8(sx8 s) {
  bfx8 h = __builtin_bit_cast(bfx8, s);
  return __builtin_convertvector(h, fx8);
}
__device__ inline fx4 mfma16(sx8 a, sx8 b, fx4 c) {
  return __builtin_amdgcn_mfma_f32_16x16x32_bf16(
      __builtin_bit_cast(bfx8, a), __builtin_bit_cast(bfx8, b), c, 0, 0, 0);
}
__device__ inline void gload_lds16(const void* g, void* l) {
  auto gp = (const __attribute__((address_space(1))) uint*)(uintptr_t)g;
  auto lp = (__attribute__((address_space(3))) uint*)(uintptr_t)l;
  __builtin_amdgcn_global_load_lds(gp, lp, 16, 0, 0);
}

// ===================== device bodies ========================================

// small bf16 MFMA GEMM body: 64x64 tile, BK=32 (teacher path)
__device__ inline void small_mfma_body(char* smem, int bx, int by,
                                       const float* __restrict__ A,
                                       const float* __restrict__ Wm,
                                       const float* __restrict__ bias,
                                       float* __restrict__ C, int N, int K) {
  ushort* ldsA = (ushort*)smem;
  ushort* ldsW = (ushort*)(smem + 4096);
  const int tid = threadIdx.x;
  const int lane = tid & 63;
  const int wv = tid >> 6;
  const int wr = wv >> 1, wc = wv & 1;
  const int row0 = by * 64;
  const int col0 = bx * 64;
  const int mt = tid >> 6;
  const int l16 = lane & 15;
  const int k8 = lane >> 4;

  const float* pA = A + (size_t)(row0 + mt * 16 + l16) * K + k8 * 8;
  int wcl = col0 + mt * 16 + l16;
  if (wcl >= N) wcl = N - 1;
  const float* pW = Wm + (size_t)wcl * K + k8 * 8;

  fx4 acc[2][2];
  const fx4 zz = {0.f, 0.f, 0.f, 0.f};
  acc[0][0] = zz; acc[0][1] = zz; acc[1][0] = zz; acc[1][1] = zz;

  sx8 ua = cvt8(*(const fx8*)pA);
  sx8 uw = cvt8(*(const fx8*)pW);
  const int NT = K >> 5;
  for (int kt = 0; kt < NT; ++kt) {
    if (kt) __syncthreads();
    *(sx8*)&ldsA[tid * 8] = ua;
    *(sx8*)&ldsW[tid * 8] = uw;
    __syncthreads();
    if (kt + 1 < NT) {
      ua = cvt8(*(const fx8*)(pA + (kt + 1) * 32));
      uw = cvt8(*(const fx8*)(pW + (kt + 1) * 32));
    }
    sx8 af[2], bf[2];
#pragma unroll
    for (int mi = 0; mi < 2; ++mi) af[mi] = *(sx8*)&ldsA[((wr * 2 + mi) * 64 + lane) * 8];
#pragma unroll
    for (int ni = 0; ni < 2; ++ni) bf[ni] = *(sx8*)&ldsW[((wc * 2 + ni) * 64 + lane) * 8];
#pragma unroll
    for (int mi = 0; mi < 2; ++mi)
#pragma unroll
      for (int ni = 0; ni < 2; ++ni) acc[mi][ni] = mfma16(af[mi], bf[ni], acc[mi][ni]);
  }
#pragma unroll
  for (int mi = 0; mi < 2; ++mi) {
    int rbase = row0 + (wr * 2 + mi) * 16 + ((lane >> 4) << 2);
#pragma unroll
    for (int ni = 0; ni < 2; ++ni) {
      int col = col0 + (wc * 2 + ni) * 16 + l16;
      if (col < N) {
        float bv = bias ? bias[col] : 0.f;
#pragma unroll
        for (int r = 0; r < 4; ++r)
          C[(size_t)(rbase + r) * N + col] = acc[mi][ni][r] + bv;
      }
    }
  }
}

// f32 exact GEMM body (student path): 32x32 tile
__device__ inline void gemm_nt32_body(char* smem, int bx, int by,
                                      const float* __restrict__ A,
                                      const float* __restrict__ W,
                                      const float* __restrict__ bias,
                                      float* __restrict__ C, int Mr, int N, int K) {
  float (*As)[33] = (float (*)[33])smem;
  float (*Ws)[33] = (float (*)[33])(smem + 4224);
  const int tid = threadIdx.x;
  const int tx = tid & 15, ty = tid >> 4;
  const int row0 = by * 32;
  const int col0 = bx * 32;
  float acc[2][2] = {{0.f, 0.f}, {0.f, 0.f}};

  for (int k0 = 0; k0 < K; k0 += 32) {
#pragma unroll
    for (int e = tid; e < 32 * 32; e += 256) {
      int r = e / 32, c = e % 32;
      int gr = row0 + r, gc = k0 + c;
      As[r][c] = (gr < Mr && gc < K) ? A[(size_t)gr * K + gc] : 0.f;
    }
#pragma unroll
    for (int e = tid; e < 32 * 32; e += 256) {
      int r = e / 32, c = e % 32;
      int gr = col0 + r, gc = k0 + c;
      Ws[r][c] = (gr < N && gc < K) ? W[(size_t)gr * K + gc] : 0.f;
    }
    __syncthreads();
#pragma unroll
    for (int kk = 0; kk < 32; ++kk) {
      float a[2], wv[2];
#pragma unroll
      for (int i = 0; i < 2; ++i) a[i] = As[ty * 2 + i][kk];
#pragma unroll
      for (int j = 0; j < 2; ++j) wv[j] = Ws[tx * 2 + j][kk];
#pragma unroll
      for (int i = 0; i < 2; ++i)
#pragma unroll
        for (int j = 0; j < 2; ++j) acc[i][j] += a[i] * wv[j];
    }
    __syncthreads();
  }
#pragma unroll
  for (int i = 0; i < 2; ++i) {
    int gr = row0 + ty * 2 + i;
    if (gr >= Mr) continue;
#pragma unroll
    for (int j = 0; j < 2; ++j) {
      int gc = col0 + tx * 2 + j;
      if (gc >= N) continue;
      float v = acc[i][j];
      if (bias) v += bias[gc];
      C[(size_t)gr * N + gc] = v;
    }
  }
}

// batchnorm body (one block per feature)
__device__ inline void bn_body(char* pool, int j,
                               const float* __restrict__ X, float* __restrict__ Y,
                               const float* __restrict__ g, const float* __restrict__ b) {
  const int tid = threadIdx.x;
  float* sf = (float*)pool;
  float vals[2];
  float s = 0.f, s2 = 0.f;
  int idx = 0;
  for (int i = tid; i < B_; i += 256, ++idx) {
    float v = X[(size_t)i * FEAT_ + j];
    vals[idx] = v;
    s += v; s2 += v * v;
  }
  sf[tid] = s; __syncthreads();
  for (int k = 128; k > 0; k >>= 1) { if (tid < k) sf[tid] += sf[tid + k]; __syncthreads(); }
  float mu = sf[0] * (1.f / B_); __syncthreads();
  sf[tid] = s2; __syncthreads();
  for (int k = 128; k > 0; k >>= 1) { if (tid < k) sf[tid] += sf[tid + k]; __syncthreads(); }
  float var = sf[0] * (1.f / B_) - mu * mu;
  float scale = rsqrtf(var + BN_EPS_) * g[j];
  float shift = b[j];
  idx = 0;
  for (int i = tid; i < B_; i += 256, ++idx)
    Y[(size_t)i * FEAT_ + j] = (vals[idx] - mu) * scale + shift;
}

// fused CE(t) + CE(s)+preds + KL body
__device__ inline void ce_kl_body(char* pool, int row,
                                  const float* __restrict__ TL,
                                  const float* __restrict__ SL,
                                  const int* __restrict__ label,
                                  float* __restrict__ acc,
                                  float* __restrict__ preds) {
  const int tid = threadIdx.x;
  const float* tp = TL + (size_t)row * NCLS_;
  const float* sp = SL + (size_t)row * NCLS_;
  float (*red)[256] = (float (*)[256])pool;
  int* ridx = (int*)(pool + 4096);
  float* sxl = (float*)(pool + 5120);

  float tv[3], sv[3];
#pragma unroll
  for (int k = 0; k < 3; ++k) {
    int j = tid + k * 256;
    tv[k] = (j < NCLS_) ? tp[j] : -INFINITY;
    sv[k] = (j < NCLS_) ? sp[j] : -INFINITY;
  }
  float mT = -INFINITY, mS = -INFINITY, sT = 0.f, sS = 0.f;
  int ai = NCLS_;
#pragma unroll
  for (int k = 0; k < 3; ++k) {
    int j = tid + k * 256;
    if (j < NCLS_) {
      mT = fmaxf(mT, tv[k]);
      sT += tv[k]; sS += sv[k];
      if (sv[k] > mS) { mS = sv[k]; ai = j; }
    }
  }
  red[0][tid] = mT; red[1][tid] = mS; red[2][tid] = sT; red[3][tid] = sS; ridx[tid] = ai;
  __syncthreads();
  for (int k = 128; k > 0; k >>= 1) {
    if (tid < k) {
      red[0][tid] = fmaxf(red[0][tid], red[0][tid + k]);
      float om = red[1][tid + k]; int oi = ridx[tid + k];
      if (om > red[1][tid] || (om == red[1][tid] && oi < ridx[tid])) { red[1][tid] = om; ridx[tid] = oi; }
      red[2][tid] += red[2][tid + k];
      red[3][tid] += red[3][tid + k];
    }
    __syncthreads();
  }
  const float MT = red[0][0], MS = red[1][0], sumT = red[2][0], sumS = red[3][0];
  const int amax = ridx[0];
  __syncthreads();
  float etr = 0.f, esr = 0.f, eth = 0.f, esh = 0.f;
#pragma unroll
  for (int k = 0; k < 3; ++k) {
    int j = tid + k * 256;
    if (j < NCLS_) {
      etr += expf(tv[k] - MT);
      esr += expf(sv[k] - MS);
      eth += expf(0.5f * (tv[k] - MT));
      esh += expf(0.5f * (sv[k] - MS));
    }
  }
  red[0][tid] = etr; red[1][tid] = esr; red[2][tid] = eth; red[3][tid] = esh;
  __syncthreads();
  for (int k = 128; k > 0; k >>= 1) {
    if (tid < k) {
      red[0][tid] += red[0][tid + k];
      red[1][tid] += red[1][tid + k];
      red[2][tid] += red[2][tid + k];
      red[3][tid] += red[3][tid + k];
    }
    __syncthreads();
  }
  const float lseT = MT + logf(red[0][0]);
  const float lseS = MS + logf(red[1][0]);
  const float ltH = 0.5f * MT + logf(red[2][0]);
  const float lsH = 0.5f * MS + logf(red[3][0]);
  __syncthreads();
  const int lab = label[row];
  float klp = 0.f;
#pragma unroll
  for (int k = 0; k < 3; ++k) {
    int j = tid + k * 256;
    if (j < NCLS_) {
      float tlp = 0.5f * tv[k] - ltH;
      float slp = 0.5f * sv[k] - lsH;
      klp += expf(tlp) * (tlp - slp);
      if (j == lab) { sxl[0] = tv[k]; sxl[1] = sv[k]; }
    }
  }
  red[0][tid] = klp;
  __syncthreads();
  for (int k = 128; k > 0; k >>= 1) {
    if (tid < k) red[0][tid] += red[0][tid + k];
    __syncthreads();
  }
  if (tid == 0) {
    float ce_t = -((1.f - LS_EPS_) * (sxl[0] - lseT) + (LS_EPS_ / NCLS_) * (sumT - NCLS_ * lseT));
    float ce_s = -((1.f - LS_EPS_) * (sxl[1] - lseS) + (LS_EPS_ / NCLS_) * (sumS - NCLS_ * lseS));
    atomicAdd(acc + 0, ce_t * (1.f / B_));
    atomicAdd(acc + 2, ce_s * (1.f / B_));
    atomicAdd(acc + 4, red[0][0] * (1.f / B_));
    preds[row] = (float)amax;
  }
}

// triplet hard-mining body
__device__ inline void triplet_body(char* pool, int which, int i,
                                    const float* __restrict__ Gt,
                                    const float* __restrict__ Gs,
                                    const int* __restrict__ label,
                                    float* __restrict__ acc) {
  const float* G = which ? Gs : Gt;
  float* a = acc + (which ? 3 : 1);
  const int tid = threadIdx.x;
  const int li = label[i];
  float* sap = (float*)pool;
  float* san = (float*)(pool + 1024);
  const float sqi = G[(size_t)i * B_ + i];
  float ap = -INFINITY, an = INFINITY;
  for (int j = tid; j < B_; j += 256) {
    float sqj = G[(size_t)j * B_ + j];
    float d2 = sqi + sqj - 2.f * G[(size_t)i * B_ + j];
    float d = sqrtf(fmaxf(d2, 1e-12f));
    if (label[j] == li) ap = fmaxf(ap, d); else an = fminf(an, d);
  }
  sap[tid] = ap; san[tid] = an; __syncthreads();
  for (int k = 128; k > 0; k >>= 1) {
    if (tid < k) {
      sap[tid] = fmaxf(sap[tid], sap[tid + k]);
      san[tid] = fminf(san[tid], san[tid + k]);
    }
    __syncthreads();
  }
  if (tid == 0) atomicAdd(a, fmaxf(sap[0] - san[0] + MARGIN_, 0.f) * (1.f / B_));
}

// per-batch Sinkhorn body (bf16 K + K^T in pool LDS)
#define SKLD 88
#define SKTLD 200
__device__ inline void sinkhorn_body(char* pool, int b,
                                     const ushort* __restrict__ sim,
                                     float* __restrict__ acc) {
  const int tid = threadIdx.x;
  ushort* Kb  = (ushort*)pool;               // 34496 B
  ushort* KbT = (ushort*)(pool + 34496);     // 30800 B
  float* r    = (float*)(pool + 65296);
  float* c    = (float*)(pool + 66080);
  float* sf   = (float*)(pool + 66432);
  float* cs1  = (float*)(pool + 67456);
  const ushort* simb = sim + (size_t)b * (M_ * N_);
  for (int e = tid; e < 196 * SKLD; e += 256) {
    int m = e / SKLD, n = e - m * SKLD;
    if (n < 77) {
      float sv = bf2f(simb[m * 77 + n]);
      ushort h = f2bf(__expf((sv - 1.f) * 10.f));
      Kb[e] = h;
      KbT[n * SKTLD + m] = h;
    } else Kb[e] = 0;
  }
  if (tid < SKLD) c[tid] = (tid < 77) ? 1.f : 0.f;
  __syncthreads();
  const float uu = 1.f / 196.f, vv = 1.f / 77.f;
  for (int it = 0; it < SINK_ITERS; ++it) {
    if (tid < 196) {
      const ushort* Km = &Kb[tid * SKLD];
      float s = 0.f;
#pragma unroll
      for (int j = 0; j < 11; ++j) {
        fx8 kf = b2f8(*(const sx8*)&Km[j * 8]);
#pragma unroll
        for (int q = 0; q < 8; ++q) s += kf[q] * c[j * 8 + q];
      }
      r[tid] = uu / s;
    }
    __syncthreads();
    if (tid < 154) {
      const int half = (tid >= 77) ? 1 : 0;
      const int n = tid - 77 * half;
      const ushort* Kn = &KbT[n * SKTLD + 96 * half];
      const int m0 = 96 * half;
      float s = 0.f;
#pragma unroll
      for (int j = 0; j < 12; ++j) {
        fx8 kf = b2f8(*(const sx8*)&Kn[j * 8]);
#pragma unroll
        for (int q = 0; q < 8; ++q) s += kf[q] * r[m0 + j * 8 + q];
      }
      if (half) {
        s += bf2f(Kn[96]) * r[192] + bf2f(Kn[97]) * r[193]
           + bf2f(Kn[98]) * r[194] + bf2f(Kn[99]) * r[195];
        cs1[n] = s;
      } else sf[n] = s;
    }
    __syncthreads();
    if (tid < 77) c[tid] = vv / (sf[tid] + cs1[tid]);
    __syncthreads();
  }
  float part = 0.f;
  for (int e = tid; e < M_ * N_; e += 256) {
    int m = e / 77, n = e - m * 77;
    part += r[m] * c[n] * bf2f(Kb[m * SKLD + n]) * bf2f(simb[e]);
  }
  sf[tid] = part; __syncthreads();
  for (int k = 128; k > 0; k >>= 1) { if (tid < k) sf[tid] += sf[tid + k]; __syncthreads(); }
  if (tid == 0) atomicAdd(acc + 5, sf[0] * (1.f / B_));
}

// ===== batched cosine sim: 3-way M-split, BK=64 phases, paired 64B staging ==
template<int H>
__device__ void sim_body(int b, const float* __restrict__ S, const ushort* __restrict__ T,
                         ushort* __restrict__ sim, ushort* lds, float* sinv_s, float* tinv_s) {
  constexpr int NTILE = (H == 2) ? 5 : 4;
  constexpr int SCH = NTILE * 128;
  constexpr int NPAIR = (SCH + 640) / 2;
  constexpr int M0 = H * 64;
  const int tid = threadIdx.x;
  const int lane = tid & 63;
  const int w = tid >> 6;

  bool val[3], isS[3], k0th[3];
  const float* pS[3];
  const ushort* pT[3];
  int rowi[3], c0[3];
#pragma unroll
  for (int j = 0; j < 3; ++j) {
    int pp = tid + j * 256;
    val[j] = (pp < NPAIR);
    int tile = pp >> 6;
    int idx = pp & 63;
    int row16 = idx & 15;
    int k8e = (idx >> 4) * 2;
    k0th[j] = (k8e == 0);
    c0[j] = tile * 128 + row16 + 16 * k8e;
    isS[j] = (tile < NTILE);
    if (isS[j]) {
      int r = M0 + tile * 16 + row16;
      int rr = r < 196 ? r : 195;
      pS[j] = S + ((size_t)b * M_ + rr) * LDIM_ + k8e * 8;
      rowi[j] = rr - M0;
      pT[j] = T;
    } else {
      int t = tile - NTILE;
      int r = t * 16 + row16;
      int rr = r < 77 ? r : 76;
      pT[j] = T + ((size_t)b * N_ + rr) * LDIM_ + k8e * 8;
      pS[j] = S;
      rowi[j] = rr;
    }
  }

  fx8 fa[3], fb[3]; sx8 ta[3], tb[3];
#pragma unroll
  for (int j = 0; j < 3; ++j) {
    if (!val[j]) continue;
    if (isS[j]) { fa[j] = *(const fx8*)pS[j]; fb[j] = *(const fx8*)(pS[j] + 8); }
    else        { ta[j] = *(const sx8*)pT[j]; tb[j] = *(const sx8*)(pT[j] + 8); }
  }

  float ss[3] = {0.f, 0.f, 0.f};
  fx4 acc[2][5];
  const fx4 zz = {0.f, 0.f, 0.f, 0.f};
#pragma unroll
  for (int i = 0; i < 2; ++i)
#pragma unroll
    for (int j = 0; j < 5; ++j) acc[i][j] = zz;

  for (int kt = 0; kt < 9; ++kt) {
    if (kt) __syncthreads();
#pragma unroll
    for (int j = 0; j < 3; ++j) {
      if (!val[j]) continue;
      if (isS[j]) {
        *(sx8*)&lds[c0[j] * 8] = cvt8(fa[j]);
        *(sx8*)&lds[(c0[j] + 16) * 8] = cvt8(fb[j]);
#pragma unroll
        for (int q = 0; q < 8; ++q) ss[j] += fa[j][q] * fa[j][q] + fb[j][q] * fb[j][q];
      } else {
        *(sx8*)&lds[c0[j] * 8] = ta[j];
        *(sx8*)&lds[(c0[j] + 16) * 8] = tb[j];
        fx8 tfa = b2f8(ta[j]), tfb = b2f8(tb[j]);
#pragma unroll
        for (int q = 0; q < 8; ++q) ss[j] += tfa[q] * tfa[q] + tfb[q] * tfb[q];
      }
    }
    if (kt < 8) {
      const int ko = (kt + 1) * 64;
#pragma unroll
      for (int j = 0; j < 3; ++j) {
        if (!val[j]) continue;
        if (isS[j]) { fa[j] = *(const fx8*)(pS[j] + ko); fb[j] = *(const fx8*)(pS[j] + ko + 8); }
        else        { ta[j] = *(const sx8*)(pT[j] + ko); tb[j] = *(const sx8*)(pT[j] + ko + 8); }
      }
    }
    __syncthreads();
#pragma unroll
    for (int q = 0; q < 2; ++q) {
      sx8 bfr[5];
#pragma unroll
      for (int ni = 0; ni < 5; ++ni)
        bfr[ni] = *(sx8*)&lds[(SCH + ni * 128 + 64 * q + lane) * 8];
#pragma unroll
      for (int mi = 0; mi < 2; ++mi) {
        int lt = w + mi * 4;
        if (lt < NTILE) {
          sx8 af = *(sx8*)&lds[(lt * 128 + 64 * q + lane) * 8];
#pragma unroll
          for (int ni = 0; ni < 5; ++ni) acc[mi][ni] = mfma16(af, bfr[ni], acc[mi][ni]);
        }
      }
    }
  }

#pragma unroll
  for (int j = 0; j < 3; ++j) {
    if (!val[j]) continue;
    float s = ss[j];
    s += __shfl_xor(s, 16);
    s += __shfl_xor(s, 32);
    if (k0th[j]) {
      float inv = 1.f / fmaxf(sqrtf(s), 1e-12f);
      if (isS[j]) sinv_s[rowi[j]] = inv;
      else        tinv_s[rowi[j]] = inv;
    }
  }
  __syncthreads();

#pragma unroll
  for (int mi = 0; mi < 2; ++mi) {
    int lt = w + mi * 4;
    if (lt >= NTILE) continue;
    int lrbase = lt * 16 + ((lane >> 4) << 2);
#pragma unroll
    for (int ni = 0; ni < 5; ++ni) {
      int col = ni * 16 + (lane & 15);
      if (col < 77) {
        float tv = tinv_s[col];
#pragma unroll
        for (int r = 0; r < 4; ++r) {
          int lrow = lrbase + r;
          int row = M0 + lrow;
          if (row < 196)
            sim[((size_t)b * M_ + row) * N_ + col] = f2bf(acc[mi][ni][r] * sinv_s[lrow] * tv);
        }
      }
    }
  }
}

// ttext 128x128 GEMM body, BK=64 (12 phases), global_load_lds staging
__device__ inline void gemm128_body(char* pool, int bx, int by,
                                    const ushort* __restrict__ A,
                                    const ushort* __restrict__ Bm,
                                    const float* __restrict__ bias,
                                    ushort* __restrict__ C) {
  ushort* ldsA = (ushort*)pool;              // 128 rows x 64 k = 16384 B
  ushort* ldsB = (ushort*)(pool + 16384);    // 16384 B
  const int tid = threadIdx.x;
  const int lane = tid & 63;
  const int w = tid >> 6;
  const int wr = w >> 1, wc = w & 1;
  const int row0 = by * 128;
  const int col0 = bx * 128;
  const int l16 = lane & 15, k8 = (lane >> 4) * 8;

  const ushort* gA0 = A + (size_t)(row0 + (2 * w) * 16 + l16) * TDIM_ + k8;
  const ushort* gA1 = A + (size_t)(row0 + (2 * w + 1) * 16 + l16) * TDIM_ + k8;
  const ushort* gB0 = Bm + (size_t)(col0 + (2 * w) * 16 + l16) * TDIM_ + k8;
  const ushort* gB1 = Bm + (size_t)(col0 + (2 * w + 1) * 16 + l16) * TDIM_ + k8;
  // tile t occupies 1024 ushorts: [t*1024 + ksl*512 + lane*8]
  ushort* lA0 = &ldsA[(2 * w) * 1024];
  ushort* lA1 = &ldsA[(2 * w + 1) * 1024];
  ushort* lB0 = &ldsB[(2 * w) * 1024];
  ushort* lB1 = &ldsB[(2 * w + 1) * 1024];

  fx4 acc[4][4];
  const fx4 zz = {0.f, 0.f, 0.f, 0.f};
#pragma unroll
  for (int i = 0; i < 4; ++i)
#pragma unroll
    for (int j = 0; j < 4; ++j) acc[i][j] = zz;

  for (int kt = 0; kt < 12; ++kt) {
    if (kt) __syncthreads();
    const int ko = kt * 64;
    gload_lds16(gA0 + ko, lA0);
    gload_lds16(gA0 + ko + 32, lA0 + 512);
    gload_lds16(gA1 + ko, lA1);
    gload_lds16(gA1 + ko + 32, lA1 + 512);
    gload_lds16(gB0 + ko, lB0);
    gload_lds16(gB0 + ko + 32, lB0 + 512);
    gload_lds16(gB1 + ko, lB1);
    gload_lds16(gB1 + ko + 32, lB1 + 512);
    asm volatile("s_waitcnt vmcnt(0)" ::: "memory");
    __syncthreads();
#pragma unroll
    for (int ksl = 0; ksl < 2; ++ksl) {
      sx8 af[4], bf[4];
#pragma unroll
      for (int mi = 0; mi < 4; ++mi)
        af[mi] = *(sx8*)&ldsA[((wr * 4 + mi) * 2 + ksl) * 512 + lane * 8];
#pragma unroll
      for (int ni = 0; ni < 4; ++ni)
        bf[ni] = *(sx8*)&ldsB[((wc * 4 + ni) * 2 + ksl) * 512 + lane * 8];
#pragma unroll
      for (int mi = 0; mi < 4; ++mi)
#pragma unroll
        for (int ni = 0; ni < 4; ++ni) acc[mi][ni] = mfma16(af[mi], bf[ni], acc[mi][ni]);
    }
  }

#pragma unroll
  for (int mi = 0; mi < 4; ++mi) {
    int rbase = row0 + wr * 64 + mi * 16 + ((lane >> 4) << 2);
#pragma unroll
    for (int ni = 0; ni < 4; ++ni) {
      int col = col0 + wc * 64 + ni * 16 + l16;
      if (col < 576) {
        float bv = bias[col];
#pragma unroll
        for (int r = 0; r < 4; ++r)
          C[(size_t)(rbase + r) * 576 + col] = f2bf(acc[mi][ni][r] + bv);
      }
    }
  }
}

// ===================== merged launch kernels ================================

// LA: stage1 (tlin MFMA + sglob f32) || prep (W cvt + acc zero) || cvt text
__global__ __launch_bounds__(256) void kernel_A(const float* __restrict__ t_img_raw,
                                                const float* __restrict__ W_tv,
                                                const float* __restrict__ b_tv,
                                                float* __restrict__ tlin,
                                                const float* __restrict__ s_glob_raw,
                                                const float* __restrict__ W_sv,
                                                const float* __restrict__ b_sv,
                                                float* __restrict__ sglob,
                                                const float* __restrict__ W_tt,
                                                ushort* __restrict__ Wbuf,
                                                float* __restrict__ acc,
                                                const float* __restrict__ text_feat,
                                                ushort* __restrict__ Abuf) {
  __shared__ __align__(16) char pool[8448];
  const int bid = blockIdx.x;
  const int tid = threadIdx.x;
  if (bid < 64) {
    small_mfma_body(pool, bid & 7, bid >> 3, t_img_raw, W_tv, b_tv, tlin, FEAT_, TDIM_);
  } else if (bid < 320) {
    int i = bid - 64;
    gemm_nt32_body(pool, i & 15, i >> 4, s_glob_raw, W_sv, b_sv, sglob, 512, FEAT_, LDIM_);
  } else if (bid < 561) {
    int pbid = bid - 320;
    if (pbid == 240) {
      if (tid < 8) acc[tid] = 0.f;
      return;
    }
    int i = pbid * 256 + tid;
    int row = i / 96;
    if (row < 576) {
      fx8 f = *(const fx8*)(W_tt + (size_t)i * 8);
      *(sx8*)(Wbuf + (size_t)i * 8) = cvt8(f);
    } else {
      sx8 z = {0, 0, 0, 0, 0, 0, 0, 0};
      *(sx8*)(Wbuf + (size_t)i * 8) = z;
    }
  } else {
    size_t i = (size_t)(bid - 561) * 256 + tid;
    fx8 f = *(const fx8*)(text_feat + i * 8);
    *(sx8*)(Abuf + i * 8) = cvt8(f);
  }
}

// LB: gemm_bf16_128 BK=64 (XCD-swizzled, global_load_lds) || bn
__global__ __launch_bounds__(256) void kernel_B(const ushort* __restrict__ Abuf,
                                                const ushort* __restrict__ Wbuf,
                                                const float* __restrict__ b_tt,
                                                ushort* __restrict__ ttext,
                                                const float* __restrict__ tlin,
                                                float* __restrict__ timg,
                                                const float* __restrict__ bn_g,
                                                const float* __restrict__ bn_b) {
  __shared__ __align__(16) char pool[32768];
  const int bid = blockIdx.x;
  if (bid < 1540) {
    const int xcd = bid & 7, wi = bid >> 3;
    const int swz = (xcd < 4 ? xcd * 193 : 772 + (xcd - 4) * 192) + wi;
    const int by = swz / 5, bx = swz - by * 5;
    gemm128_body(pool, bx, by, Abuf, Wbuf, b_tt, ttext);
  } else {
    bn_body(pool, bid - 1540, tlin, timg, bn_g, bn_b);
  }
}

// LC: sim (XCD-swizzled, BK=64 paired staging) || stage2
__global__ __launch_bounds__(256) void kernel_C(const float* __restrict__ s_local,
                                                const ushort* __restrict__ ttext,
                                                ushort* __restrict__ sim,
                                                const float* __restrict__ timg,
                                                const float* __restrict__ W_ct,
                                                const float* __restrict__ b_ct,
                                                float* __restrict__ tlog,
                                                const float* __restrict__ sglob,
                                                const float* __restrict__ W_cs,
                                                const float* __restrict__ b_cs,
                                                float* __restrict__ slog,
                                                float* __restrict__ gram_t,
                                                float* __restrict__ gram_s) {
  __shared__ __align__(16) char pool[21120];
  const int bid = blockIdx.x;
  if (bid < 1536) {
    ushort* lds = (ushort*)pool;
    float* sinv_s = (float*)(pool + 20480);
    float* tinv_s = (float*)(pool + 20800);
    const int swz = (bid & 7) * 192 + (bid >> 3);
    const int b = swz / 3;
    const int q = swz - b * 3;
    if (q == 0)      sim_body<0>(b, s_local, ttext, sim, lds, sinv_s, tinv_s);
    else if (q == 1) sim_body<1>(b, s_local, ttext, sim, lds, sinv_s, tinv_s);
    else             sim_body<2>(b, s_local, ttext, sim, lds, sinv_s, tinv_s);
  } else {
    int i = bid - 1536;
    if (i < 80) {
      small_mfma_body(pool, i % 10, i / 10, timg, W_ct, b_ct, tlog, NCLS_, FEAT_);
    } else if (i < 400) {
      int j = i - 80;
      gemm_nt32_body(pool, j % 20, j / 20, sglob, W_cs, b_cs, slog, 512, NCLS_, FEAT_);
    } else if (i < 464) {
      int j = i - 400;
      small_mfma_body(pool, j & 7, j >> 3, timg, timg, nullptr, gram_t, 512, FEAT_);
    } else {
      int j = i - 464;
      small_mfma_body(pool, j & 7, j >> 3, sglob, sglob, nullptr, gram_s, 512, LDIM_);
    }
  }
}

// LD: sinkhorn || ce_kl (+preds) || triplet x2, with device-wide completion
__global__ __launch_bounds__(256) void kernel_D(const ushort* __restrict__ sim,
                                                const float* __restrict__ tlog,
                                                const float* __restrict__ slog,
                                                const float* __restrict__ gram_t,
                                                const float* __restrict__ gram_s,
                                                const int* __restrict__ label,
                                                float* __restrict__ acc,
                                                float* __restrict__ out) {
  __shared__ __align__(16) char pool[67840];
  const int bid = blockIdx.x;
  if (bid < 512) {
    sinkhorn_body(pool, bid, sim, acc);
  } else if (bid < 1024) {
    ce_kl_body(pool, bid - 512, tlog, slog, label, acc, out + 1);
  } else {
    int i = bid - 1024;
    triplet_body(pool, i >> 9, i & 511, gram_t, gram_s, label, acc);
  }
  if (threadIdx.x == 0) {
    __threadfence();
    uint prev = atomicAdd((uint*)(acc + 6), 1u);
    if (prev == 2047u) {
      float a0 = atomicAdd(acc + 0, 0.f);
      float a1 = atomicAdd(acc + 1, 0.f);
      float a2 = atomicAdd(acc + 2, 0.f);
      float a3 = atomicAdd(acc + 3, 0.f);
      float a4 = atomicAdd(acc + 4, 0.f);
      float a5 = atomicAdd(acc + 5, 0.f);
      out[0] = a0 + a1 + a2 + a3 + a4 + (1.f - a5);
    }
  }
}

// ---------------------------------------------------------------------------
extern "C" void kernel_launch(void* const* d_in, const int* in_sizes, int n_in,
                              void* d_out, int out_size, void* d_ws, size_t ws_size,
                              hipStream_t stream) {
  const float* text_feat  = (const float*)d_in[0];
  const float* t_img_raw  = (const float*)d_in[1];
  const float* s_glob_raw = (const float*)d_in[2];
  const float* s_local    = (const float*)d_in[3];
  const int*   label      = (const int*)d_in[4];
  const float* W_tv = (const float*)d_in[5];
  const float* b_tv = (const float*)d_in[6];
  const float* W_tt = (const float*)d_in[7];
  const float* b_tt = (const float*)d_in[8];
  const float* W_sv = (const float*)d_in[9];
  const float* b_sv = (const float*)d_in[10];
  const float* bn_g = (const float*)d_in[11];
  const float* bn_b = (const float*)d_in[12];
  const float* W_ct = (const float*)d_in[13];
  const float* b_ct = (const float*)d_in[14];
  const float* W_cs = (const float*)d_in[15];
  const float* b_cs = (const float*)d_in[16];
  float* out = (float*)d_out;
  float* ws = (float*)d_ws;

  float* tlin   = ws;
  float* timg   = tlin + 262144;
  float* sglob  = timg + 262144;
  float* tlog   = sglob + 262144;
  float* slog   = tlog + 323584;
  float* gram_t = slog + 323584;
  float* gram_s = gram_t + 262144;
  float* acc    = gram_s + 262144;
  ushort* Wbuf  = (ushort*)(acc + 8);
  ushort* ttext = Wbuf + 491520;
  ushort* Abuf  = ttext + 22708224;
  ushort* sim   = Abuf;   // alias; Abuf dead before sim written

  dim3 blk(256);

  // LA: stage1 || prep || cvt
  kernel_A<<<15345, blk, 0, stream>>>(t_img_raw, W_tv, b_tv, tlin,
                                      s_glob_raw, W_sv, b_sv, sglob,
                                      W_tt, Wbuf, acc, text_feat, Abuf);
  // LB: ttext GEMM (BK=64) || bn
  kernel_B<<<2052, blk, 0, stream>>>(Abuf, Wbuf, b_tt, ttext, tlin, timg, bn_g, bn_b);
  // LC: sim (BK=64) || stage2
  kernel_C<<<2064, blk, 0, stream>>>(s_local, ttext, sim,
                                     timg, W_ct, b_ct, tlog,
                                     sglob, W_cs, b_cs, slog, gram_t, gram_s);
  // LD: sinkhorn || ce_kl || triplet, fused finalize
  kernel_D<<<2048, blk, 0, stream>>>(sim, tlog, slog, gram_t, gram_s, label, acc, out);
}